// Round 4
// baseline (369.309 us; speedup 1.0000x reference)
//
#include <hip/hip_runtime.h>
#include <cstdint>

#define LT 24
#define NSITE (LT*LT*LT*LT)      // 331776
#define HALF  (NSITE/2)          // 165888
#define NCOMPLEX (4*NSITE*9)     // 11943936 complex elements total

// block-role layout (256 threads/block)
#define NB_UPD 648               // HALF/256: stout update, even dir-0 links
#define NB_ODD 648               // HALF/256: dir-0 odd pass-through
#define NB_CPY 2048              // dense interleave copy of dirs 1-3
#define CPY_Q0 (NSITE*9/4)       // 746496: first re-float4 quad of dir-1
#define CPY_NQ (3*NSITE*9/4)     // 2239488 quads in dirs 1-3

typedef float vf4 __attribute__((ext_vector_type(4)));

struct C3 { float re[9]; float im[9]; };

// 9 contiguous floats, base only guaranteed 4B-aligned.
__device__ __forceinline__ void load9(float* d, const float* __restrict__ p) {
    float4 a, b;
    __builtin_memcpy(&a, p,     16);
    __builtin_memcpy(&b, p + 4, 16);
    d[0]=a.x; d[1]=a.y; d[2]=a.z; d[3]=a.w;
    d[4]=b.x; d[5]=b.y; d[6]=b.z; d[7]=b.w;
    d[8]=p[8];
}

__device__ __forceinline__ void loadM(C3& m, const float* __restrict__ re,
                                      const float* __restrict__ im, int off) {
    load9(m.re, re + off);
    load9(m.im, im + off);
}

// store matrix as interleaved (re,im) pairs at complex-element base cbase.
__device__ __forceinline__ void storeM(float2* __restrict__ out, int cbase, const C3& m) {
    float4 v;
    v.x=m.re[0]; v.y=m.im[0]; v.z=m.re[1]; v.w=m.im[1];
    __builtin_memcpy(out + cbase,     &v, 16);
    v.x=m.re[2]; v.y=m.im[2]; v.z=m.re[3]; v.w=m.im[3];
    __builtin_memcpy(out + cbase + 2, &v, 16);
    v.x=m.re[4]; v.y=m.im[4]; v.z=m.re[5]; v.w=m.im[5];
    __builtin_memcpy(out + cbase + 4, &v, 16);
    v.x=m.re[6]; v.y=m.im[6]; v.z=m.re[7]; v.w=m.im[7];
    __builtin_memcpy(out + cbase + 6, &v, 16);
    float2 w; w.x=m.re[8]; w.y=m.im[8];
    out[cbase + 8] = w;
}

// o = a @ b
__device__ __forceinline__ void mmul(C3& o, const C3& a, const C3& b) {
#pragma unroll
    for (int r = 0; r < 3; ++r) {
#pragma unroll
        for (int c = 0; c < 3; ++c) {
            float sr = 0.f, si = 0.f;
#pragma unroll
            for (int k = 0; k < 3; ++k) {
                float ar = a.re[r*3+k], ai = a.im[r*3+k];
                float br = b.re[k*3+c], bi = b.im[k*3+c];
                sr += ar*br - ai*bi;
                si += ar*bi + ai*br;
            }
            o.re[r*3+c] = sr; o.im[r*3+c] = si;
        }
    }
}

// f += cr * (a @ b)
__device__ __forceinline__ void mmul_acc(C3& f, const C3& a, const C3& b, float cr) {
#pragma unroll
    for (int r = 0; r < 3; ++r) {
#pragma unroll
        for (int c = 0; c < 3; ++c) {
            float sr = 0.f, si = 0.f;
#pragma unroll
            for (int k = 0; k < 3; ++k) {
                float ar = a.re[r*3+k], ai = a.im[r*3+k];
                float br = b.re[k*3+c], bi = b.im[k*3+c];
                sr += ar*br - ai*bi;
                si += ar*bi + ai*br;
            }
            f.re[r*3+c] += cr * sr; f.im[r*3+c] += cr * si;
        }
    }
}

// o = a @ b^dagger
__device__ __forceinline__ void mmul_adjB(C3& o, const C3& a, const C3& b) {
#pragma unroll
    for (int r = 0; r < 3; ++r) {
#pragma unroll
        for (int c = 0; c < 3; ++c) {
            float sr = 0.f, si = 0.f;
#pragma unroll
            for (int k = 0; k < 3; ++k) {
                float ar = a.re[r*3+k], ai = a.im[r*3+k];
                float br = b.re[c*3+k], bi = b.im[c*3+k];
                sr += ar*br + ai*bi;
                si += ai*br - ar*bi;
            }
            o.re[r*3+c] = sr; o.im[r*3+c] = si;
        }
    }
}

// o = a^dagger @ b
__device__ __forceinline__ void madjA_mul(C3& o, const C3& a, const C3& b) {
#pragma unroll
    for (int r = 0; r < 3; ++r) {
#pragma unroll
        for (int c = 0; c < 3; ++c) {
            float sr = 0.f, si = 0.f;
#pragma unroll
            for (int k = 0; k < 3; ++k) {
                float ar = a.re[k*3+r], ai = a.im[k*3+r];
                float br = b.re[k*3+c], bi = b.im[k*3+c];
                sr += ar*br + ai*bi;
                si += ar*bi - ai*br;
            }
            o.re[r*3+c] = sr; o.im[r*3+c] = si;
        }
    }
}

// idx in [0, HALF) -> site of given parity (0=even updated subset, 1=odd)
__device__ __forceinline__ int site_from_idx(int idx, int parity,
                                             int& t, int& z, int& y, int& x) {
    int xh = idx % 12;  int r = idx / 12;
    y = r % LT; r /= LT;
    z = r % LT; t = r / LT;
    x = 2 * xh + ((t + z + y + parity) & 1);
    return ((t * LT + z) * LT + y) * LT + x;
}

// ---- Fused kernel: block-role split --------------------------------------
// blocks [0, NB_UPD):              stout update of even dir-0 links
//                                  (latency-bound: 10 waves/CU demand)
// blocks [NB_UPD, NB_UPD+NB_ODD):  dir-0 odd pass-through copy
// blocks [NB_UPD+NB_ODD, ...):     dense interleave copy of dirs 1-3
// Copy blocks stream through leftover wave slots while update blocks sit on
// load latency + the serial matexp chain -> time ~ max(update, copy), not sum.
// __launch_bounds__(256,4): cap VGPR at 128 so 16 waves/CU are co-resident
// (update needs 10 -> 6 slots/CU left for copy during the overlap phase).
__global__ __launch_bounds__(256, 4)
void stout_all(const float* __restrict__ xre, const float* __restrict__ xim,
               const float* __restrict__ coeff, float2* __restrict__ out) {
    const int bid = blockIdx.x;

    if (bid >= NB_UPD + NB_ODD) {
        // ---- dense interleave copy of dirs 1-3 ----
        const vf4* __restrict__ re4 = (const vf4*)xre;
        const vf4* __restrict__ im4 = (const vf4*)xim;
        vf4* __restrict__ o4 = (vf4*)out;
        const int tid = (bid - (NB_UPD + NB_ODD)) * 256 + threadIdx.x;
        for (int j = tid; j < CPY_NQ; j += NB_CPY * 256) {
            const int q = CPY_Q0 + j;
            vf4 r = re4[q];
            vf4 i = im4[q];
            vf4 o0 = { r.x, i.x, r.y, i.y };
            vf4 o1 = { r.z, i.z, r.w, i.w };
            __builtin_nontemporal_store(o0, o4 + 2*q);
            __builtin_nontemporal_store(o1, o4 + 2*q + 1);
        }
        return;
    }

    if (bid >= NB_UPD) {
        // ---- dir-0 odd-site pass-through copy ----
        const int idx = (bid - NB_UPD) * 256 + threadIdx.x;
        int t, z, y, x;
        const int s = site_from_idx(idx, 1, t, z, y, x);
        C3 m;
        loadM(m, xre, xim, s * 9);
        storeM(out, s * 9, m);
        return;
    }

    // ---- stout update of even dir-0 links (proven monolith body) ----
    const int idx = bid * 256 + threadIdx.x;

    int t, z, y, x;
    const int s = site_from_idx(idx, 0, t, z, y, x);

    float c[6];
#pragma unroll
    for (int i = 0; i < 6; ++i)
        c[i] = 0.07957747154594768f * atanf(coeff[i]);

    int tp = (t + 1 < LT) ? t + 1 : 0;
    int zp = (z + 1 < LT) ? z + 1 : 0;  int zm = (z > 0) ? z - 1 : LT - 1;
    int yp = (y + 1 < LT) ? y + 1 : 0;  int ym = (y > 0) ? y - 1 : LT - 1;
    int xp = (x + 1 < LT) ? x + 1 : 0;  int xm = (x > 0) ? x - 1 : LT - 1;

    const int stt = ((tp * LT + z) * LT + y) * LT + x;   // s + T^
    const int spv[3]  = { ((t  * LT + zp) * LT + y ) * LT + x,
                          ((t  * LT + z ) * LT + yp) * LT + x,
                          ((t  * LT + z ) * LT + y ) * LT + xp };
    const int smv[3]  = { ((t  * LT + zm) * LT + y ) * LT + x,
                          ((t  * LT + z ) * LT + ym) * LT + x,
                          ((t  * LT + z ) * LT + y ) * LT + xm };
    const int smtv[3] = { ((tp * LT + zm) * LT + y ) * LT + x,
                          ((tp * LT + z ) * LT + ym) * LT + x,
                          ((tp * LT + z ) * LT + y ) * LT + xm };

    C3 f;
#pragma unroll
    for (int j = 0; j < 9; ++j) { f.re[j] = 0.f; f.im[j] = 0.f; }

    C3 A, B, Cm, tmp;
#pragma unroll
    for (int i = 0; i < 3; ++i) {
        const int d = i + 1;
        // forward staple: x[nu](s) @ (x0(s+nu) @ x[nu](s+T)^dag)
        loadM(A, xre, xim, (d * NSITE + s) * 9);
        loadM(B,  xre, xim, (     spv[i])        * 9);
        loadM(Cm, xre, xim, (d * NSITE + stt)    * 9);
        mmul_adjB(tmp, B, Cm);
        mmul_acc(f, A, tmp, c[2 * i]);
        // backward staple: (x[nu](s-nu)^dag @ x0(s-nu)) @ x[nu](s-nu+T)
        loadM(A,  xre, xim, (d * NSITE + smv[i]) * 9);
        loadM(B,  xre, xim, (     smv[i])        * 9);
        madjA_mul(tmp, A, B);
        loadM(Cm, xre, xim, (d * NSITE + smtv[i])* 9);
        mmul_acc(f, tmp, Cm, c[2 * i + 1]);
    }

    // xupd = x0(s) (even site)
    C3 U;
    loadM(U, xre, xim, s * 9);

    // M = f @ U^dag ; A = 0.5(M - M^dag) ; Zt = A - tr(A)/3 * I
    C3 Mm;
    mmul_adjB(Mm, f, U);
    C3 Zt;
#pragma unroll
    for (int r = 0; r < 3; ++r) {
#pragma unroll
        for (int cq = 0; cq < 3; ++cq) {
            Zt.re[r*3+cq] = 0.5f * (Mm.re[r*3+cq] - Mm.re[cq*3+r]);
            Zt.im[r*3+cq] = 0.5f * (Mm.im[r*3+cq] + Mm.im[cq*3+r]);
        }
    }
    float trIm = (Zt.im[0] + Zt.im[4] + Zt.im[8]) / 3.0f;
    Zt.im[0] -= trIm; Zt.im[4] -= trIm; Zt.im[8] -= trIm;

    // matexp: scale by 0.5^4, 12-term Horner, 4 squarings
#pragma unroll
    for (int j = 0; j < 9; ++j) { Zt.re[j] *= 0.0625f; Zt.im[j] *= 0.0625f; }

    C3 E;
#pragma unroll
    for (int j = 0; j < 9; ++j) { E.re[j] = 0.f; E.im[j] = 0.f; }
    E.re[0] = 1.f; E.re[4] = 1.f; E.re[8] = 1.f;

    C3 Tm;
#pragma unroll
    for (int k = 12; k >= 1; --k) {
        mmul(Tm, Zt, E);
        const float invk = 1.0f / (float)k;
#pragma unroll
        for (int j = 0; j < 9; ++j) {
            E.re[j] = Tm.re[j] * invk;
            E.im[j] = Tm.im[j] * invk;
        }
        E.re[0] += 1.f; E.re[4] += 1.f; E.re[8] += 1.f;
    }
#pragma unroll
    for (int q = 0; q < 4; ++q) {
        mmul(Tm, E, E);
        E = Tm;
    }

    // ymu = E @ U  (even site: xmu_fix = 0)
    C3 Y;
    mmul(Y, E, U);
    storeM(out, s * 9, Y);   // dir-0 updated link
}

extern "C" void kernel_launch(void* const* d_in, const int* in_sizes, int n_in,
                              void* d_out, int out_size, void* d_ws, size_t ws_size,
                              hipStream_t stream) {
    const float* xre   = (const float*)d_in[0];
    const float* xim   = (const float*)d_in[1];
    const float* coeff = (const float*)d_in[2];

    const int nblocks = NB_UPD + NB_ODD + NB_CPY;   // 3344
    stout_all<<<nblocks, 256, 0, stream>>>(xre, xim, coeff, (float2*)d_out);
}

// Round 5
// 215.967 us; speedup vs baseline: 1.7100x; 1.7100x over previous
//
#include <hip/hip_runtime.h>
#include <cstdint>

#define LT 24
#define NSITE (LT*LT*LT*LT)      // 331776
#define HALF  (NSITE/2)          // 165888
#define NCOMPLEX (4*NSITE*9)     // 11943936 complex elements total

// block-role layout: 3240 blocks of 256 threads, quintet pattern
// [update, odd-copy, dense-copy, dense-copy, dense-copy]
#define NB_TOT 3240
#define NB_CPY 1944                  // 3 of every 5 blocks
#define CPY_THREADS (NB_CPY*256)     // 497664
#define Q0D (NSITE*9/2)              // 1492992: first out-quad of dir 1
#define NQD (3*NSITE*9/2)            // 4478976 out-quads in dirs 1-3 (= 9*CPY_THREADS)

typedef float vf4 __attribute__((ext_vector_type(4)));

struct C3 { float re[9]; float im[9]; };

// 9 contiguous floats, base only guaranteed 4B-aligned.
__device__ __forceinline__ void load9(float* d, const float* __restrict__ p) {
    float4 a, b;
    __builtin_memcpy(&a, p,     16);
    __builtin_memcpy(&b, p + 4, 16);
    d[0]=a.x; d[1]=a.y; d[2]=a.z; d[3]=a.w;
    d[4]=b.x; d[5]=b.y; d[6]=b.z; d[7]=b.w;
    d[8]=p[8];
}

__device__ __forceinline__ void loadM(C3& m, const float* __restrict__ re,
                                      const float* __restrict__ im, int off) {
    load9(m.re, re + off);
    load9(m.im, im + off);
}

// store matrix as interleaved (re,im) pairs at complex-element base cbase.
__device__ __forceinline__ void storeM(float2* __restrict__ out, int cbase, const C3& m) {
    float4 v;
    v.x=m.re[0]; v.y=m.im[0]; v.z=m.re[1]; v.w=m.im[1];
    __builtin_memcpy(out + cbase,     &v, 16);
    v.x=m.re[2]; v.y=m.im[2]; v.z=m.re[3]; v.w=m.im[3];
    __builtin_memcpy(out + cbase + 2, &v, 16);
    v.x=m.re[4]; v.y=m.im[4]; v.z=m.re[5]; v.w=m.im[5];
    __builtin_memcpy(out + cbase + 4, &v, 16);
    v.x=m.re[6]; v.y=m.im[6]; v.z=m.re[7]; v.w=m.im[7];
    __builtin_memcpy(out + cbase + 6, &v, 16);
    float2 w; w.x=m.re[8]; w.y=m.im[8];
    out[cbase + 8] = w;
}

// o = a @ b
__device__ __forceinline__ void mmul(C3& o, const C3& a, const C3& b) {
#pragma unroll
    for (int r = 0; r < 3; ++r) {
#pragma unroll
        for (int c = 0; c < 3; ++c) {
            float sr = 0.f, si = 0.f;
#pragma unroll
            for (int k = 0; k < 3; ++k) {
                float ar = a.re[r*3+k], ai = a.im[r*3+k];
                float br = b.re[k*3+c], bi = b.im[k*3+c];
                sr += ar*br - ai*bi;
                si += ar*bi + ai*br;
            }
            o.re[r*3+c] = sr; o.im[r*3+c] = si;
        }
    }
}

// f += cr * (a @ b)
__device__ __forceinline__ void mmul_acc(C3& f, const C3& a, const C3& b, float cr) {
#pragma unroll
    for (int r = 0; r < 3; ++r) {
#pragma unroll
        for (int c = 0; c < 3; ++c) {
            float sr = 0.f, si = 0.f;
#pragma unroll
            for (int k = 0; k < 3; ++k) {
                float ar = a.re[r*3+k], ai = a.im[r*3+k];
                float br = b.re[k*3+c], bi = b.im[k*3+c];
                sr += ar*br - ai*bi;
                si += ar*bi + ai*br;
            }
            f.re[r*3+c] += cr * sr; f.im[r*3+c] += cr * si;
        }
    }
}

// o = a @ b^dagger
__device__ __forceinline__ void mmul_adjB(C3& o, const C3& a, const C3& b) {
#pragma unroll
    for (int r = 0; r < 3; ++r) {
#pragma unroll
        for (int c = 0; c < 3; ++c) {
            float sr = 0.f, si = 0.f;
#pragma unroll
            for (int k = 0; k < 3; ++k) {
                float ar = a.re[r*3+k], ai = a.im[r*3+k];
                float br = b.re[c*3+k], bi = b.im[c*3+k];
                sr += ar*br + ai*bi;
                si += ai*br - ar*bi;
            }
            o.re[r*3+c] = sr; o.im[r*3+c] = si;
        }
    }
}

// o = a^dagger @ b
__device__ __forceinline__ void madjA_mul(C3& o, const C3& a, const C3& b) {
#pragma unroll
    for (int r = 0; r < 3; ++r) {
#pragma unroll
        for (int c = 0; c < 3; ++c) {
            float sr = 0.f, si = 0.f;
#pragma unroll
            for (int k = 0; k < 3; ++k) {
                float ar = a.re[k*3+r], ai = a.im[k*3+r];
                float br = b.re[k*3+c], bi = b.im[k*3+c];
                sr += ar*br + ai*bi;
                si += ar*bi - ai*br;
            }
            o.re[r*3+c] = sr; o.im[r*3+c] = si;
        }
    }
}

// idx in [0, HALF) -> site of given parity (0=even updated subset, 1=odd)
__device__ __forceinline__ int site_from_idx(int idx, int parity,
                                             int& t, int& z, int& y, int& x) {
    int xh = idx % 12;  int r = idx / 12;
    y = r % LT; r /= LT;
    z = r % LT; t = r / LT;
    x = 2 * xh + ((t + z + y + parity) & 1);
    return ((t * LT + z) * LT + y) * LT + x;
}

// ---- Fused kernel, role interleaved by bid % 5 -----------------------------
// role 0: stout update of even dir-0 links (latency-bound, 10 waves/CU demand)
// role 1: dir-0 odd pass-through copy
// role 2-4: dense interleave copy of dirs 1-3 (float2 loads, dense 16B NT stores)
// Round-robin roles => every CU holds a mix at all times; the copy uses the
// memory pipe the (L3-warm) update barely touches => time ~ max, not sum.
// NO occupancy cap: round 4 proved capping VGPR to <90 floats spills matexp
// catastrophically (hbm_bytes 294->904 MB). Default ~156 VGPR, 3 waves/SIMD.
__global__ __launch_bounds__(256)
void stout_all(const float* __restrict__ xre, const float* __restrict__ xim,
               const float* __restrict__ coeff, float2* __restrict__ out) {
    const int bid  = blockIdx.x;
    const int role = bid % 5;
    const int sub  = bid / 5;

    if (role >= 2) {
        // ---- dense interleave copy of dirs 1-3 ----
        // out-quad q = {re[2q], im[2q], re[2q+1], im[2q+1]}: 2x 8B loads
        // (512B/wave dense) + 1x 16B NT store (1KB/wave dense).
        const float2* __restrict__ re2 = (const float2*)xre;
        const float2* __restrict__ im2 = (const float2*)xim;
        vf4* __restrict__ o4 = (vf4*)out;
        const int cid = sub * 3 + (role - 2);          // 0..NB_CPY-1
        int q = Q0D + cid * 256 + threadIdx.x;
#pragma unroll
        for (int it = 0; it < 9; ++it, q += CPY_THREADS) {
            float2 r = re2[q];
            float2 i = im2[q];
            vf4 o = { r.x, i.x, r.y, i.y };
            __builtin_nontemporal_store(o, o4 + q);
        }
        return;
    }

    if (role == 1) {
        // ---- dir-0 odd-site pass-through copy ----
        const int idx = sub * 256 + threadIdx.x;
        int t, z, y, x;
        const int s = site_from_idx(idx, 1, t, z, y, x);
        C3 m;
        loadM(m, xre, xim, s * 9);
        storeM(out, s * 9, m);
        return;
    }

    // ---- role 0: stout update of even dir-0 links (proven monolith body) ----
    const int idx = sub * 256 + threadIdx.x;

    int t, z, y, x;
    const int s = site_from_idx(idx, 0, t, z, y, x);

    float c[6];
#pragma unroll
    for (int i = 0; i < 6; ++i)
        c[i] = 0.07957747154594768f * atanf(coeff[i]);

    int tp = (t + 1 < LT) ? t + 1 : 0;
    int zp = (z + 1 < LT) ? z + 1 : 0;  int zm = (z > 0) ? z - 1 : LT - 1;
    int yp = (y + 1 < LT) ? y + 1 : 0;  int ym = (y > 0) ? y - 1 : LT - 1;
    int xp = (x + 1 < LT) ? x + 1 : 0;  int xm = (x > 0) ? x - 1 : LT - 1;

    const int stt = ((tp * LT + z) * LT + y) * LT + x;   // s + T^
    const int spv[3]  = { ((t  * LT + zp) * LT + y ) * LT + x,
                          ((t  * LT + z ) * LT + yp) * LT + x,
                          ((t  * LT + z ) * LT + y ) * LT + xp };
    const int smv[3]  = { ((t  * LT + zm) * LT + y ) * LT + x,
                          ((t  * LT + z ) * LT + ym) * LT + x,
                          ((t  * LT + z ) * LT + y ) * LT + xm };
    const int smtv[3] = { ((tp * LT + zm) * LT + y ) * LT + x,
                          ((tp * LT + z ) * LT + ym) * LT + x,
                          ((tp * LT + z ) * LT + y ) * LT + xm };

    C3 f;
#pragma unroll
    for (int j = 0; j < 9; ++j) { f.re[j] = 0.f; f.im[j] = 0.f; }

    C3 A, B, Cm, tmp;
#pragma unroll
    for (int i = 0; i < 3; ++i) {
        const int d = i + 1;
        // forward staple: x[nu](s) @ (x0(s+nu) @ x[nu](s+T)^dag)
        loadM(A, xre, xim, (d * NSITE + s) * 9);
        loadM(B,  xre, xim, (     spv[i])        * 9);
        loadM(Cm, xre, xim, (d * NSITE + stt)    * 9);
        mmul_adjB(tmp, B, Cm);
        mmul_acc(f, A, tmp, c[2 * i]);
        // backward staple: (x[nu](s-nu)^dag @ x0(s-nu)) @ x[nu](s-nu+T)
        loadM(A,  xre, xim, (d * NSITE + smv[i]) * 9);
        loadM(B,  xre, xim, (     smv[i])        * 9);
        madjA_mul(tmp, A, B);
        loadM(Cm, xre, xim, (d * NSITE + smtv[i])* 9);
        mmul_acc(f, tmp, Cm, c[2 * i + 1]);
    }

    // xupd = x0(s) (even site)
    C3 U;
    loadM(U, xre, xim, s * 9);

    // M = f @ U^dag ; A = 0.5(M - M^dag) ; Zt = A - tr(A)/3 * I
    C3 Mm;
    mmul_adjB(Mm, f, U);
    C3 Zt;
#pragma unroll
    for (int r = 0; r < 3; ++r) {
#pragma unroll
        for (int cq = 0; cq < 3; ++cq) {
            Zt.re[r*3+cq] = 0.5f * (Mm.re[r*3+cq] - Mm.re[cq*3+r]);
            Zt.im[r*3+cq] = 0.5f * (Mm.im[r*3+cq] + Mm.im[cq*3+r]);
        }
    }
    float trIm = (Zt.im[0] + Zt.im[4] + Zt.im[8]) / 3.0f;
    Zt.im[0] -= trIm; Zt.im[4] -= trIm; Zt.im[8] -= trIm;

    // matexp: scale by 0.5^4, 12-term Horner, 4 squarings
#pragma unroll
    for (int j = 0; j < 9; ++j) { Zt.re[j] *= 0.0625f; Zt.im[j] *= 0.0625f; }

    C3 E;
#pragma unroll
    for (int j = 0; j < 9; ++j) { E.re[j] = 0.f; E.im[j] = 0.f; }
    E.re[0] = 1.f; E.re[4] = 1.f; E.re[8] = 1.f;

    C3 Tm;
#pragma unroll
    for (int k = 12; k >= 1; --k) {
        mmul(Tm, Zt, E);
        const float invk = 1.0f / (float)k;
#pragma unroll
        for (int j = 0; j < 9; ++j) {
            E.re[j] = Tm.re[j] * invk;
            E.im[j] = Tm.im[j] * invk;
        }
        E.re[0] += 1.f; E.re[4] += 1.f; E.re[8] += 1.f;
    }
#pragma unroll
    for (int q = 0; q < 4; ++q) {
        mmul(Tm, E, E);
        E = Tm;
    }

    // ymu = E @ U  (even site: xmu_fix = 0)
    C3 Y;
    mmul(Y, E, U);
    storeM(out, s * 9, Y);   // dir-0 updated link
}

extern "C" void kernel_launch(void* const* d_in, const int* in_sizes, int n_in,
                              void* d_out, int out_size, void* d_ws, size_t ws_size,
                              hipStream_t stream) {
    const float* xre   = (const float*)d_in[0];
    const float* xim   = (const float*)d_in[1];
    const float* coeff = (const float*)d_in[2];

    stout_all<<<NB_TOT, 256, 0, stream>>>(xre, xim, coeff, (float2*)d_out);
}